// Round 3
// baseline (195.538 us; speedup 1.0000x reference)
//
#include <hip/hip_runtime.h>
#include <hip/hip_bf16.h>

// MoE MLP (top-2 of 8 experts), T=4096 tokens, D=1024, W=1024.
// R9: (1) GEMM K-loop -> double-buffered prefetch (T3 minimum 2-phase):
//         stage tile t+1 into LDS buf^1 BEFORE computing tile t; ONE
//         __syncthreads per K-step (its implicit vmcnt(0) lands the prefetch
//         after MFMA covered the latency). LDS 32->64KB, launch_bounds(256,2).
//     (2) build_lists hidden under w2 transpose: lists_w2t_kernel block 0 =
//         ballot list-build, blocks 1..512 = 4 w2-transpose tiles each
//         (1024 thr). gemm1 is pure GEMM again (R8 appended the transpose
//         tail to gemm1's grid, delaying gemm2 -- not a real overlap).
// Retained: 128x128 tile BK=64 granule-XOR swizzle, XCD map expert=bid&7,
//           fused w1-transpose+router pre, CAP=1536, gload_lds w16 staging.

#define T_TOKENS 4096
#define DD 1024
#define EE 8
#define WW 1024
#define CAP 1536              // per-expert capacity (expected ~1024, sigma ~28)
#define BM 128
#define BN 128
#define BK 64
#define MT (CAP / BM)         // 12 m-tiles max per expert
#define NT (WW / BN)          // 8 n-tiles
#define GEMM_BLOCKS (EE * MT * NT)  // 768
#define TR1_BLOCKS 2048       // w1 transpose blocks (in pre)

typedef short bf16x8 __attribute__((ext_vector_type(8)));
typedef float f32x4 __attribute__((ext_vector_type(4)));

__device__ __forceinline__ void gload_lds16(const void* g, void* l) {
  __builtin_amdgcn_global_load_lds((__attribute__((address_space(1))) void*)(g),
                                   (__attribute__((address_space(3))) void*)(l),
                                   16, 0, 0);
}

__device__ __forceinline__ float bf2f(unsigned short u) {
  union { unsigned int i; float f; } v; v.i = (unsigned int)u << 16; return v.f;
}

// ---------------- pre: w1 transpose + router (unchanged from R8) ----------------
// blocks [0,2048): w1 transpose; [2048,3072): router, 1 wave = 1 token.
__global__ __launch_bounds__(256) void pre_kernel(
    const float* __restrict__ w1, const float* __restrict__ x,
    const float* __restrict__ rw,
    __hip_bfloat16* __restrict__ w1t, __hip_bfloat16* __restrict__ xb,
    int* __restrict__ sel, float* __restrict__ wpair)
{
  __shared__ float tile[64][65];
  int b = blockIdx.x;
  if (b < TR1_BLOCKS) {
    // w1 [D=1024, E*W=8192] -> w1t [8192, 1024] bf16
    int bx = b & 15;            // dst col tile (16 tiles of 64 over 1024)
    int by = b >> 4;            // 0..127 -> dst rows 0..8191
    const float* src = w1;
    __hip_bfloat16* dst = w1t;
    long src_ld = EE * WW, dst_ld = DD;
    long c0 = (long)bx * 64;    // dst col = src row
    long r0 = (long)by * 64;    // dst row = src col
    int tx = threadIdx.x & 15, ty = threadIdx.x >> 4;
#pragma unroll
    for (int i = 0; i < 4; i++) {
      int sr = ty + 16 * i;
      f32x4 v = *(const f32x4*)(src + (c0 + sr) * src_ld + r0 + tx * 4);
      tile[sr][tx * 4 + 0] = v[0];
      tile[sr][tx * 4 + 1] = v[1];
      tile[sr][tx * 4 + 2] = v[2];
      tile[sr][tx * 4 + 3] = v[3];
    }
    __syncthreads();
#pragma unroll
    for (int i = 0; i < 4; i++) {
      int dr = ty + 16 * i;
      union { __hip_bfloat16 hb[4]; ushort4 u4; } pk;
#pragma unroll
      for (int j = 0; j < 4; j++)
        pk.hb[j] = __float2bfloat16(tile[tx * 4 + j][dr]);
      *(ushort4*)((unsigned short*)dst + (r0 + dr) * dst_ld + c0 + tx * 4) = pk.u4;
    }
  } else {
    // router: one wave per token, fp32 logits, top-2, no atomics
    int lane = threadIdx.x & 63;
    int wave = threadIdx.x >> 6;
    int t = (b - TR1_BLOCKS) * 4 + wave;
    const float* xrow = x + (size_t)t * DD;
    float acc[EE];
#pragma unroll
    for (int e = 0; e < EE; e++) acc[e] = 0.f;
#pragma unroll
    for (int i = 0; i < DD / 64; i++) {
      int d = lane + i * 64;
      float xv = xrow[d];
      xb[t * DD + d] = __float2bfloat16(xv);   // fused x -> bf16
#pragma unroll
      for (int e = 0; e < EE; e++) acc[e] += xv * rw[e * DD + d];
    }
#pragma unroll
    for (int e = 0; e < EE; e++) {
#pragma unroll
      for (int off = 32; off > 0; off >>= 1)
        acc[e] += __shfl_down(acc[e], off, 64);
    }
    if (lane == 0) {
      float p[EE];
#pragma unroll
      for (int e = 0; e < EE; e++) p[e] = 1.f / (1.f + expf(-acc[e]));
      // top-2, ties -> lowest index (matches jax.lax.top_k stable ordering)
      int e0 = 0; float b0 = p[0];
      for (int e = 1; e < EE; e++) if (p[e] > b0) { b0 = p[e]; e0 = e; }
      int e1 = -1; float b1 = -1.f;
      for (int e = 0; e < EE; e++) {
        if (e == e0) continue;
        if (p[e] > b1) { b1 = p[e]; e1 = e; }
      }
      float s = b0 + b1 + 1e-20f;
      sel[t] = e0 | (e1 << 8);
      wpair[2 * t]     = b0 / s;
      wpair[2 * t + 1] = b1 / s;
    }
  }
}

// ---------------- lists + w2 transpose: block 0 = ballot list-build (serial,
// ~7us) hidden under blocks 1..512 = w2 transpose (4 tiles each, BW-bound) ----
__global__ __launch_bounds__(1024) void lists_w2t_kernel(
    const int* __restrict__ sel, int* __restrict__ counts,
    int* __restrict__ idx, int* __restrict__ tslot,
    const float* __restrict__ w2, __hip_bfloat16* __restrict__ w2t)
{
  __shared__ float tile[4][64][65];   // 66,560 B (transpose blocks)
  __shared__ int lcnt[EE];
  int b = blockIdx.x;
  int tid = threadIdx.x;
  if (b == 0) {
    // ---- build per-expert token lists (exact R8 logic, 1024 threads) ----
    int lane = tid & 63;
    if (tid < EE) lcnt[tid] = 0;
    __syncthreads();
    unsigned long long lower = (1ull << lane) - 1;
#pragma unroll
    for (int j = 0; j < T_TOKENS / 1024; j++) {
      int t = j * 1024 + tid;
      int s = sel[t];
      int e0 = s & 0xff, e1 = (s >> 8) & 0xff;
      int slot0 = 0, slot1 = 0;
#pragma unroll
      for (int e = 0; e < EE; e++) {
        unsigned long long m0 = __ballot(e0 == e);
        unsigned long long m1 = __ballot(e1 == e);
        int c0 = __popcll(m0), c1 = __popcll(m1);
        int base = 0;
        if (lane == 0 && (c0 + c1) > 0) base = atomicAdd(&lcnt[e], c0 + c1);
        base = __shfl(base, 0, 64);
        if (e0 == e) slot0 = base + __popcll(m0 & lower);
        if (e1 == e) slot1 = base + c0 + __popcll(m1 & lower);
      }
      int p0 = e0 * CAP + slot0, p1 = e1 * CAP + slot1;
      idx[p0] = t; idx[p1] = t;
      tslot[2 * t] = p0; tslot[2 * t + 1] = p1;
    }
    __syncthreads();
    if (tid < EE) counts[tid] = lcnt[tid];
  } else {
    // ---- w2 transpose: 4 tiles per block, quarter-block per tile ----
    // w2 [E*W, D] expert slice e: [W,D] -> w2t[e] [D, W] bf16
    int q = tid >> 8, tq = tid & 255;
    int z = (b - 1) * 4 + q;          // 0..2047
    int bx = z & 15;                  // dst col tile over W
    int zz = z >> 4;                  // 0..127
    int e = zz >> 4, yy = zz & 15;
    const float* src = w2 + (long)e * WW * DD;
    __hip_bfloat16* dst = w2t + (long)e * DD * WW;
    long c0 = (long)bx * 64;          // dst col = src row (W dim)
    long r0 = (long)yy * 64;          // dst row = src col (D dim)
    int tx = tq & 15, ty = tq >> 4;
#pragma unroll
    for (int i = 0; i < 4; i++) {
      int sr = ty + 16 * i;
      f32x4 v = *(const f32x4*)(src + (c0 + sr) * DD + r0 + tx * 4);
      tile[q][sr][tx * 4 + 0] = v[0];
      tile[q][sr][tx * 4 + 1] = v[1];
      tile[q][sr][tx * 4 + 2] = v[2];
      tile[q][sr][tx * 4 + 3] = v[3];
    }
    __syncthreads();
#pragma unroll
    for (int i = 0; i < 4; i++) {
      int dr = ty + 16 * i;
      union { __hip_bfloat16 hb[4]; ushort4 u4; } pk;
#pragma unroll
      for (int j = 0; j < 4; j++)
        pk.hb[j] = __float2bfloat16(tile[q][tx * 4 + j][dr]);
      *(ushort4*)((unsigned short*)dst + (r0 + dr) * WW + c0 + tx * 4) = pk.u4;
    }
  }
}

// ---------------- grouped GEMM1: h = gather(xb) @ W1_e, act = relu(h)^2 ----------------
// 128x128 tile, BK=64, double-buffered prefetch K-loop (1 barrier per K-step).
// XCD map: expert = bid & 7.
__global__ __launch_bounds__(256, 2) void gemm1_kernel(
    const __hip_bfloat16* __restrict__ xb, const __hip_bfloat16* __restrict__ w1t,
    const int* __restrict__ counts, const int* __restrict__ idx,
    __hip_bfloat16* __restrict__ act)
{
  // buf0: As@0, Bs@16K ; buf1: As@32K, Bs@48K
  __shared__ __attribute__((aligned(16))) char smem[65536];
  int bid = blockIdx.x;
  int e = bid & 7;
  int i = bid >> 3;
  int mt = i >> 3, nt = i & 7;
  int n_e = counts[e];
  if (mt * BM >= n_e) return;

  int tid = threadIdx.x;
  int lane = tid & 63;
  int wave = __builtin_amdgcn_readfirstlane(tid >> 6);
  int wm = (wave >> 1) * 64, wn = (wave & 1) * 64;
  int m16 = lane & 15, qd = lane >> 4;

  // staging: granule = 16B (8 bf16); 8 granule-cols/row; slot s -> row s>>3,
  // swizzled col (s&7)^(r&7); LDS dest linear (gload_lds is base+lane*16).
  const __hip_bfloat16* gA[4];
  const __hip_bfloat16* gB[4];
#pragma unroll
  for (int i2 = 0; i2 < 4; i2++) {
    int s = i2 * 256 + tid;
    int r = s >> 3;
    int q = (s & 7) ^ (r & 7);
    int rowA = mt * BM + r;
    int slot = rowA < n_e ? rowA : n_e - 1;   // clamp tail rows to valid slot
    int tok = idx[e * CAP + slot];
    gA[i2] = xb + (size_t)tok * DD + q * 8;
    gB[i2] = w1t + ((size_t)e * WW + nt * BN + r) * DD + q * 8;
  }
  int ldsOff[4];                     // short-index offsets within a buffer
#pragma unroll
  for (int i2 = 0; i2 < 4; i2++) ldsOff[i2] = (i2 * 256 + wave * 64) * 8;

  int aoff[4][2], boff[4][2];
#pragma unroll
  for (int mi = 0; mi < 4; mi++) {
    int r = wm + mi * 16 + m16;
#pragma unroll
    for (int h = 0; h < 2; h++)
      aoff[mi][h] = (r * 8 + ((qd + h * 4) ^ (r & 7))) * 8;
  }
#pragma unroll
  for (int ni = 0; ni < 4; ni++) {
    int r = wn + ni * 16 + m16;
#pragma unroll
    for (int h = 0; h < 2; h++)
      boff[ni][h] = (r * 8 + ((qd + h * 4) ^ (r & 7))) * 8;
  }

  f32x4 zero = {0.f, 0.f, 0.f, 0.f};
  f32x4 acc[4][4];
#pragma unroll
  for (int mi = 0; mi < 4; mi++)
#pragma unroll
    for (int ni = 0; ni < 4; ni++) acc[mi][ni] = zero;

  // prologue: stage tile 0 into buf0
#pragma unroll
  for (int i2 = 0; i2 < 4; i2++) {
    gload_lds16(gA[i2], (short*)smem + ldsOff[i2]);
    gload_lds16(gB[i2], (short*)(smem + 16384) + ldsOff[i2]);
  }
  __syncthreads();

  int cur = 0;
  for (int k0 = 0; k0 < DD; k0 += BK) {
    if (k0 + BK < DD) {              // prefetch next tile into buf^1
      char* nb = smem + (cur ^ 1) * 32768;
#pragma unroll
      for (int i2 = 0; i2 < 4; i2++) {
        gload_lds16(gA[i2] + k0 + BK, (short*)nb + ldsOff[i2]);
        gload_lds16(gB[i2] + k0 + BK, (short*)(nb + 16384) + ldsOff[i2]);
      }
    }
    short* As = (short*)(smem + cur * 32768);
    short* Bs = (short*)(smem + cur * 32768 + 16384);
#pragma unroll
    for (int h = 0; h < 2; h++) {
      bf16x8 af[4], bfr[4];
#pragma unroll
      for (int mi = 0; mi < 4; mi++) af[mi] = *(const bf16x8*)(As + aoff[mi][h]);
#pragma unroll
      for (int ni = 0; ni < 4; ni++) bfr[ni] = *(const bf16x8*)(Bs + boff[ni][h]);
#pragma unroll
      for (int mi = 0; mi < 4; mi++)
#pragma unroll
        for (int ni = 0; ni < 4; ni++)
          acc[mi][ni] = __builtin_amdgcn_mfma_f32_16x16x32_bf16(
              af[mi], bfr[ni], acc[mi][ni], 0, 0, 0);
    }
    __syncthreads();                 // drains vmcnt (prefetch landed) + lgkm
    cur ^= 1;
  }

  // epilogue: relu^2 -> bf16 act[(e*CAP + slot)][col]
#pragma unroll
  for (int mi = 0; mi < 4; mi++) {
#pragma unroll
    for (int reg = 0; reg < 4; reg++) {
      int rowt = mt * BM + wm + mi * 16 + qd * 4 + reg;
      if (rowt < n_e) {
#pragma unroll
        for (int ni = 0; ni < 4; ni++) {
          float v = acc[mi][ni][reg];
          v = v > 0.f ? v * v : 0.f;
          int col = nt * BN + wn + ni * 16 + m16;
          act[((size_t)e * CAP + rowt) * WW + col] = __float2bfloat16(v);
        }
      }
    }
  }
}

// ---------------- grouped GEMM2: y = act @ W2_e (raw bf16 y, no atomics) ----------------
__global__ __launch_bounds__(256, 2) void gemm2_kernel(
    const __hip_bfloat16* __restrict__ act, const __hip_bfloat16* __restrict__ w2t,
    const int* __restrict__ counts, __hip_bfloat16* __restrict__ y)
{
  __shared__ __attribute__((aligned(16))) char smem[65536];
  int bid = blockIdx.x;
  int e = bid & 7;
  int i = bid >> 3;
  int mt = i >> 3, nt = i & 7;
  int n_e = counts[e];
  if (mt * BM >= n_e) return;

  int tid = threadIdx.x;
  int lane = tid & 63;
  int wave = __builtin_amdgcn_readfirstlane(tid >> 6);
  int wm = (wave >> 1) * 64, wn = (wave & 1) * 64;
  int m16 = lane & 15, qd = lane >> 4;

  const __hip_bfloat16* gA[4];
  const __hip_bfloat16* gB[4];
#pragma unroll
  for (int i2 = 0; i2 < 4; i2++) {
    int s = i2 * 256 + tid;
    int r = s >> 3;
    int q = (s & 7) ^ (r & 7);
    // rows >= n_e: poison bytes, but row-isolated in MFMA -> discarded rows only
    gA[i2] = act + ((size_t)e * CAP + mt * BM + r) * WW + q * 8;
    gB[i2] = w2t + ((size_t)e * DD + nt * BN + r) * WW + q * 8;
  }
  int ldsOff[4];
#pragma unroll
  for (int i2 = 0; i2 < 4; i2++) ldsOff[i2] = (i2 * 256 + wave * 64) * 8;

  int aoff[4][2], boff[4][2];
#pragma unroll
  for (int mi = 0; mi < 4; mi++) {
    int r = wm + mi * 16 + m16;
#pragma unroll
    for (int h = 0; h < 2; h++)
      aoff[mi][h] = (r * 8 + ((qd + h * 4) ^ (r & 7))) * 8;
  }
#pragma unroll
  for (int ni = 0; ni < 4; ni++) {
    int r = wn + ni * 16 + m16;
#pragma unroll
    for (int h = 0; h < 2; h++)
      boff[ni][h] = (r * 8 + ((qd + h * 4) ^ (r & 7))) * 8;
  }

  f32x4 zero = {0.f, 0.f, 0.f, 0.f};
  f32x4 acc[4][4];
#pragma unroll
  for (int mi = 0; mi < 4; mi++)
#pragma unroll
    for (int ni = 0; ni < 4; ni++) acc[mi][ni] = zero;

#pragma unroll
  for (int i2 = 0; i2 < 4; i2++) {
    gload_lds16(gA[i2], (short*)smem + ldsOff[i2]);
    gload_lds16(gB[i2], (short*)(smem + 16384) + ldsOff[i2]);
  }
  __syncthreads();

  int cur = 0;
  for (int k0 = 0; k0 < WW; k0 += BK) {
    if (k0 + BK < WW) {
      char* nb = smem + (cur ^ 1) * 32768;
#pragma unroll
      for (int i2 = 0; i2 < 4; i2++) {
        gload_lds16(gA[i2] + k0 + BK, (short*)nb + ldsOff[i2]);
        gload_lds16(gB[i2] + k0 + BK, (short*)(nb + 16384) + ldsOff[i2]);
      }
    }
    short* As = (short*)(smem + cur * 32768);
    short* Bs = (short*)(smem + cur * 32768 + 16384);
#pragma unroll
    for (int h = 0; h < 2; h++) {
      bf16x8 af[4], bfr[4];
#pragma unroll
      for (int mi = 0; mi < 4; mi++) af[mi] = *(const bf16x8*)(As + aoff[mi][h]);
#pragma unroll
      for (int ni = 0; ni < 4; ni++) bfr[ni] = *(const bf16x8*)(Bs + boff[ni][h]);
#pragma unroll
      for (int mi = 0; mi < 4; mi++)
#pragma unroll
        for (int ni = 0; ni < 4; ni++)
          acc[mi][ni] = __builtin_amdgcn_mfma_f32_16x16x32_bf16(
              af[mi], bfr[ni], acc[mi][ni], 0, 0, 0);
    }
    __syncthreads();
    cur ^= 1;
  }

  // epilogue: raw y (routing weights applied in combine)
#pragma unroll
  for (int mi = 0; mi < 4; mi++) {
#pragma unroll
    for (int reg = 0; reg < 4; reg++) {
      int slot = mt * BM + wm + mi * 16 + qd * 4 + reg;
      if (slot < n_e) {
#pragma unroll
        for (int ni = 0; ni < 4; ni++) {
          int col = nt * BN + wn + ni * 16 + m16;
          y[((size_t)e * CAP + slot) * DD + col] = __float2bfloat16(acc[mi][ni][reg]);
        }
      }
    }
  }
}

// ---------------- combine: out[t] = w0*y[slot0] + w1*y[slot1] ----------------
__global__ __launch_bounds__(256) void combine_kernel(
    const __hip_bfloat16* __restrict__ y, const int* __restrict__ tslot,
    const float* __restrict__ wpair, float* __restrict__ out)
{
  int t = blockIdx.x;
  int c = threadIdx.x * 4;
  int s0 = tslot[2 * t], s1 = tslot[2 * t + 1];
  float w0 = wpair[2 * t], w1 = wpair[2 * t + 1];
  const unsigned short* yu = (const unsigned short*)y;
  ushort4 a = *(const ushort4*)(yu + (size_t)s0 * DD + c);
  ushort4 bq = *(const ushort4*)(yu + (size_t)s1 * DD + c);
  f32x4 o;
  o[0] = w0 * bf2f(a.x) + w1 * bf2f(bq.x);
  o[1] = w0 * bf2f(a.y) + w1 * bf2f(bq.y);
  o[2] = w0 * bf2f(a.z) + w1 * bf2f(bq.z);
  o[3] = w0 * bf2f(a.w) + w1 * bf2f(bq.w);
  *(f32x4*)(out + (size_t)t * DD + c) = o;
}

extern "C" void kernel_launch(void* const* d_in, const int* in_sizes, int n_in,
                              void* d_out, int out_size, void* d_ws, size_t ws_size,
                              hipStream_t stream)
{
  const float* x  = (const float*)d_in[0];
  const float* rw = (const float*)d_in[1];
  const float* w1 = (const float*)d_in[2];
  const float* w2 = (const float*)d_in[3];
  float* out = (float*)d_out;

  char* ws = (char*)d_ws;
  __hip_bfloat16* xb  = (__hip_bfloat16*)ws;  ws += (size_t)T_TOKENS * DD * 2;
  __hip_bfloat16* w1t = (__hip_bfloat16*)ws;  ws += (size_t)EE * WW * DD * 2;
  __hip_bfloat16* w2t = (__hip_bfloat16*)ws;  ws += (size_t)EE * DD * WW * 2;
  __hip_bfloat16* act = (__hip_bfloat16*)ws;  ws += (size_t)EE * CAP * WW * 2;
  __hip_bfloat16* y   = (__hip_bfloat16*)ws;  ws += (size_t)EE * CAP * DD * 2;
  int*   counts = (int*)ws;                   ws += 256;
  int*   idx    = (int*)ws;                   ws += (size_t)EE * CAP * 4;
  int*   sel    = (int*)ws;                   ws += (size_t)T_TOKENS * 4;
  int*   tslot  = (int*)ws;                   ws += (size_t)T_TOKENS * 8;
  float* wpair  = (float*)ws;                 ws += (size_t)T_TOKENS * 8;

  // k1: w1 transpose + router (sel/wpair)
  pre_kernel<<<TR1_BLOCKS + T_TOKENS / 4, 256, 0, stream>>>(
      w1, x, rw, w1t, xb, sel, wpair);
  // k2: block 0 = list build (hidden), blocks 1..512 = w2 transpose
  lists_w2t_kernel<<<513, 1024, 0, stream>>>(sel, counts, idx, tslot, w2, w2t);
  // k3/k4: grouped GEMMs (double-buffered prefetch)
  gemm1_kernel<<<GEMM_BLOCKS, 256, 0, stream>>>(xb, w1t, counts, idx, act);
  gemm2_kernel<<<GEMM_BLOCKS, 256, 0, stream>>>(act, w2t, counts, y);
  combine_kernel<<<T_TOKENS, 256, 0, stream>>>(y, tslot, wpair, out);
}

// Round 4
// 188.835 us; speedup vs baseline: 1.0355x; 1.0355x over previous
//
#include <hip/hip_runtime.h>
#include <hip/hip_bf16.h>

// MoE MLP (top-2 of 8 experts), T=4096 tokens, D=1024, W=1024.
// R10: (1) GEMMs reverted to R8's proven single-buffer m97 structure
//          (R9's 64KB-LDS dbuf cut occupancy 3->2 blocks/CU: the m132
//          regression pattern; cross-round deltas show gemms are ~10us each,
//          so the dbuf's ~40% GEMM cost showed up as R9's +6us).
//      (2) Transposes rewritten at 128x128 tiles (were 64x64): 512B read
//          segments / 256B write segments (were 256B/128B), 4x fewer blocks,
//          bf16 LDS scatter-transpose ([128][132] pad -> bounded conflicts).
//          Cross-round inference says pre + w2t is the largest kernel-side
//          cost (~30-40us vs ~11us BW floor).
// Retained: 128x128 GEMM tile BK=64 granule-XOR swizzle, XCD map expert=bid&7,
//           ballot build_lists, CAP=1536, gload_lds w16 staging.

#define T_TOKENS 4096
#define DD 1024
#define EE 8
#define WW 1024
#define CAP 1536              // per-expert capacity (expected ~1024, sigma ~28)
#define BM 128
#define BN 128
#define BK 64
#define MT (CAP / BM)         // 12 m-tiles max per expert
#define NT (WW / BN)          // 8 n-tiles
#define GEMM_BLOCKS (EE * MT * NT)  // 768
#define TR1_BLOCKS 512        // w1 transpose blocks (128x128 tiles, in pre)
#define TR2_BLOCKS 512        // w2 transpose blocks (in gemm1 grid)
#define TLD 132               // LDS transpose tile row stride (shorts), pad=4

typedef short bf16x8 __attribute__((ext_vector_type(8)));
typedef float f32x4 __attribute__((ext_vector_type(4)));

__device__ __forceinline__ void gload_lds16(const void* g, void* l) {
  __builtin_amdgcn_global_load_lds((__attribute__((address_space(1))) void*)(g),
                                   (__attribute__((address_space(3))) void*)(l),
                                   16, 0, 0);
}

__device__ __forceinline__ float bf2f(unsigned short u) {
  union { unsigned int i; float f; } v; v.i = (unsigned int)u << 16; return v.f;
}

__device__ __forceinline__ unsigned short f2bf_u(float f) {
  __hip_bfloat16 h = __float2bfloat16(f);
  union { __hip_bfloat16 h; unsigned short u; } c; c.h = h; return c.u;
}

// ---- 128x128 fp32->bf16 transpose tile through LDS ----
// src: fp32, row-major, leading dim src_ld; tile origin src[r0..r0+128][c0..c0+128].
// dst: bf16 (ushort), leading dim dst_ld; dst[(c0+c)*dst_ld + r0 + r] = src[r][c].
// lds: 128*TLD shorts (33792 B). 256 threads.
__device__ __forceinline__ void transpose_tile_128(
    const float* __restrict__ src, long src_ld, long r0, long c0,
    unsigned short* __restrict__ dst, long dst_ld, unsigned short* lds)
{
  int tid = threadIdx.x;
  int cq = tid & 31;            // covers 4 src cols
  int rb = tid >> 5;            // row base 0..7
  // phase 1: coalesced 512B row reads, scatter bf16 into transposed LDS tile
#pragma unroll
  for (int i = 0; i < 16; i++) {
    int r = rb + i * 8;
    f32x4 v = *(const f32x4*)(src + (r0 + r) * src_ld + c0 + cq * 4);
#pragma unroll
    for (int j = 0; j < 4; j++)
      lds[(cq * 4 + j) * TLD + r] = f2bf_u(v[j]);
  }
  __syncthreads();
  // phase 2: read rows of transposed tile, 16B (ushort8) coalesced global stores
#pragma unroll
  for (int it = 0; it < 8; it++) {
    int slot = it * 256 + tid;
    int c = slot >> 4;          // dst row within tile
    int m = slot & 15;          // 8-elem chunk within row
    const unsigned short* p = lds + (size_t)c * TLD + m * 8;
    uint2 lo = *(const uint2*)(p);
    uint2 hi = *(const uint2*)(p + 4);
    uint4 o; o.x = lo.x; o.y = lo.y; o.z = hi.x; o.w = hi.y;
    *(uint4*)(dst + (c0 + c) * dst_ld + r0 + m * 8) = o;
  }
}

// ---------------- pre: w1 transpose (128x128 tiles) + router ----------------
// blocks [0,512): w1 transpose; [512,1536): router, 1 wave = 1 token.
__global__ __launch_bounds__(256) void pre_kernel(
    const float* __restrict__ w1, const float* __restrict__ x,
    const float* __restrict__ rw,
    __hip_bfloat16* __restrict__ w1t, __hip_bfloat16* __restrict__ xb,
    int* __restrict__ sel, float* __restrict__ wpair)
{
  __shared__ unsigned short lds_t[128 * TLD];   // 33792 B
  int b = blockIdx.x;
  if (b < TR1_BLOCKS) {
    // w1 [D=1024, E*W=8192] -> w1t [8192, 1024] bf16
    int bn = b >> 3;            // n-tile 0..63 (src col / dst row)
    int bd = b & 7;             // d-tile 0..7  (src row / dst col)
    transpose_tile_128(w1, EE * WW, (long)bd * 128, (long)bn * 128,
                       (unsigned short*)w1t, DD, lds_t);
  } else {
    // router: one wave per token, fp32 logits, top-2, no atomics
    int lane = threadIdx.x & 63;
    int wave = threadIdx.x >> 6;
    int t = (b - TR1_BLOCKS) * 4 + wave;
    const float* xrow = x + (size_t)t * DD;
    float acc[EE];
#pragma unroll
    for (int e = 0; e < EE; e++) acc[e] = 0.f;
#pragma unroll
    for (int i = 0; i < DD / 64; i++) {
      int d = lane + i * 64;
      float xv = xrow[d];
      xb[t * DD + d] = __float2bfloat16(xv);   // fused x -> bf16
#pragma unroll
      for (int e = 0; e < EE; e++) acc[e] += xv * rw[e * DD + d];
    }
#pragma unroll
    for (int e = 0; e < EE; e++) {
#pragma unroll
      for (int off = 32; off > 0; off >>= 1)
        acc[e] += __shfl_down(acc[e], off, 64);
    }
    if (lane == 0) {
      float p[EE];
#pragma unroll
      for (int e = 0; e < EE; e++) p[e] = 1.f / (1.f + expf(-acc[e]));
      // top-2, ties -> lowest index (matches jax.lax.top_k stable ordering)
      int e0 = 0; float b0 = p[0];
      for (int e = 1; e < EE; e++) if (p[e] > b0) { b0 = p[e]; e0 = e; }
      int e1 = -1; float b1 = -1.f;
      for (int e = 0; e < EE; e++) {
        if (e == e0) continue;
        if (p[e] > b1) { b1 = p[e]; e1 = e; }
      }
      float s = b0 + b1 + 1e-20f;
      sel[t] = e0 | (e1 << 8);
      wpair[2 * t]     = b0 / s;
      wpair[2 * t + 1] = b1 / s;
    }
  }
}

// ---------------- build per-expert token lists (1 block, wave-ballot agg) ----------------
__global__ __launch_bounds__(1024) void build_lists(
    const int* __restrict__ sel, int* __restrict__ counts,
    int* __restrict__ idx, int* __restrict__ tslot)
{
  __shared__ int lcnt[EE];
  int tid = threadIdx.x, lane = tid & 63;
  if (tid < EE) lcnt[tid] = 0;
  __syncthreads();
  unsigned long long lower = (1ull << lane) - 1;
#pragma unroll
  for (int j = 0; j < T_TOKENS / 1024; j++) {
    int t = j * 1024 + tid;
    int s = sel[t];
    int e0 = s & 0xff, e1 = (s >> 8) & 0xff;
    int slot0 = 0, slot1 = 0;
#pragma unroll
    for (int e = 0; e < EE; e++) {
      unsigned long long m0 = __ballot(e0 == e);
      unsigned long long m1 = __ballot(e1 == e);
      int c0 = __popcll(m0), c1 = __popcll(m1);
      int base = 0;
      if (lane == 0 && (c0 + c1) > 0) base = atomicAdd(&lcnt[e], c0 + c1);
      base = __shfl(base, 0, 64);
      if (e0 == e) slot0 = base + __popcll(m0 & lower);
      if (e1 == e) slot1 = base + c0 + __popcll(m1 & lower);
    }
    int p0 = e0 * CAP + slot0, p1 = e1 * CAP + slot1;
    idx[p0] = t; idx[p1] = t;
    tslot[2 * t] = p0; tslot[2 * t + 1] = p1;
  }
  __syncthreads();
  if (tid < EE) counts[tid] = lcnt[tid];
}

// ---------------- grouped GEMM1 (+ fused w2 transpose blocks) ----------------
// blocks [0,768): h = gather(xb) @ W1_e, act = relu(h)^2, 128x128 tile, BK=64.
// blocks [768, 768+512): w2 [E*W,D] -> w2t[e] [D,W] bf16, 128x128 tiles.
// XCD map: expert = bid & 7 (round-robin dispatch puts expert e on XCD e;
// per-expert B slab 2MB + A subset ~2MB stay L2-resident).
__global__ __launch_bounds__(256, 3) void gemm1_kernel(
    const __hip_bfloat16* __restrict__ xb, const __hip_bfloat16* __restrict__ w1t,
    const int* __restrict__ counts, const int* __restrict__ idx,
    __hip_bfloat16* __restrict__ act,
    const float* __restrict__ w2, __hip_bfloat16* __restrict__ w2t)
{
  __shared__ __attribute__((aligned(16))) char smem[128 * TLD * 2]; // 33792B
  int bid = blockIdx.x;
  if (bid >= GEMM_BLOCKS) {
    // ---- w2 transpose: expert slice [W,D] -> w2t[e] [D,W] ----
    int z = bid - GEMM_BLOCKS;      // 0..511
    int e = z >> 6;                 // 64 tiles per expert
    int t2 = z & 63;
    int bw = t2 >> 3;               // w-tile (src row / dst col)
    int bdd = t2 & 7;               // d-tile (src col / dst row)
    transpose_tile_128(w2 + (long)e * WW * DD, DD,
                       (long)bw * 128, (long)bdd * 128,
                       (unsigned short*)(w2t + (long)e * DD * WW), WW,
                       (unsigned short*)smem);
    return;
  }
  short* As = (short*)smem;
  short* Bs = (short*)(smem + 16384);
  int e = bid & 7;
  int i = bid >> 3;
  int mt = i >> 3, nt = i & 7;
  int n_e = counts[e];
  if (mt * BM >= n_e) return;

  int tid = threadIdx.x;
  int lane = tid & 63;
  int wave = __builtin_amdgcn_readfirstlane(tid >> 6);
  int wm = (wave >> 1) * 64, wn = (wave & 1) * 64;
  int m16 = lane & 15, qd = lane >> 4;

  // staging: granule = 16B (8 bf16); 8 granule-cols/row; slot s -> row s>>3,
  // swizzled col (s&7)^(r&7); LDS dest linear (gload_lds is base+lane*16).
  const __hip_bfloat16* gA[4];
  const __hip_bfloat16* gB[4];
#pragma unroll
  for (int i2 = 0; i2 < 4; i2++) {
    int s = i2 * 256 + tid;
    int r = s >> 3;
    int q = (s & 7) ^ (r & 7);
    int rowA = mt * BM + r;
    int slot = rowA < n_e ? rowA : n_e - 1;   // clamp tail rows to valid slot
    int tok = idx[e * CAP + slot];
    gA[i2] = xb + (size_t)tok * DD + q * 8;
    gB[i2] = w1t + ((size_t)e * WW + nt * BN + r) * DD + q * 8;
  }
  short* ldsA[4];
  short* ldsB[4];
#pragma unroll
  for (int i2 = 0; i2 < 4; i2++) {
    ldsA[i2] = As + (i2 * 256 + wave * 64) * 8;
    ldsB[i2] = Bs + (i2 * 256 + wave * 64) * 8;
  }

  int aoff[4][2], boff[4][2];
#pragma unroll
  for (int mi = 0; mi < 4; mi++) {
    int r = wm + mi * 16 + m16;
#pragma unroll
    for (int h = 0; h < 2; h++)
      aoff[mi][h] = (r * 8 + ((qd + h * 4) ^ (r & 7))) * 8;
  }
#pragma unroll
  for (int ni = 0; ni < 4; ni++) {
    int r = wn + ni * 16 + m16;
#pragma unroll
    for (int h = 0; h < 2; h++)
      boff[ni][h] = (r * 8 + ((qd + h * 4) ^ (r & 7))) * 8;
  }

  f32x4 zero = {0.f, 0.f, 0.f, 0.f};
  f32x4 acc[4][4];
#pragma unroll
  for (int mi = 0; mi < 4; mi++)
#pragma unroll
    for (int ni = 0; ni < 4; ni++) acc[mi][ni] = zero;

  for (int k0 = 0; k0 < DD; k0 += BK) {
#pragma unroll
    for (int i2 = 0; i2 < 4; i2++) gload_lds16(gA[i2] + k0, ldsA[i2]);
#pragma unroll
    for (int i2 = 0; i2 < 4; i2++) gload_lds16(gB[i2] + k0, ldsB[i2]);
    __syncthreads();
#pragma unroll
    for (int h = 0; h < 2; h++) {
      bf16x8 af[4], bfr[4];
#pragma unroll
      for (int mi = 0; mi < 4; mi++) af[mi] = *(const bf16x8*)(As + aoff[mi][h]);
#pragma unroll
      for (int ni = 0; ni < 4; ni++) bfr[ni] = *(const bf16x8*)(Bs + boff[ni][h]);
#pragma unroll
      for (int mi = 0; mi < 4; mi++)
#pragma unroll
        for (int ni = 0; ni < 4; ni++)
          acc[mi][ni] = __builtin_amdgcn_mfma_f32_16x16x32_bf16(
              af[mi], bfr[ni], acc[mi][ni], 0, 0, 0);
    }
    __syncthreads();
  }

  // epilogue: relu^2 -> bf16 act[(e*CAP + slot)][col]
#pragma unroll
  for (int mi = 0; mi < 4; mi++) {
#pragma unroll
    for (int reg = 0; reg < 4; reg++) {
      int rowt = mt * BM + wm + mi * 16 + qd * 4 + reg;
      if (rowt < n_e) {
#pragma unroll
        for (int ni = 0; ni < 4; ni++) {
          float v = acc[mi][ni][reg];
          v = v > 0.f ? v * v : 0.f;
          int col = nt * BN + wn + ni * 16 + m16;
          act[((size_t)e * CAP + rowt) * WW + col] = __float2bfloat16(v);
        }
      }
    }
  }
}

// ---------------- grouped GEMM2: y = act @ W2_e (raw bf16 y, no atomics) ----------------
__global__ __launch_bounds__(256, 3) void gemm2_kernel(
    const __hip_bfloat16* __restrict__ act, const __hip_bfloat16* __restrict__ w2t,
    const int* __restrict__ counts, __hip_bfloat16* __restrict__ y)
{
  __shared__ __attribute__((aligned(16))) char smem[32768];
  short* As = (short*)smem;
  short* Bs = (short*)(smem + 16384);
  int bid = blockIdx.x;
  int e = bid & 7;
  int i = bid >> 3;
  int mt = i >> 3, nt = i & 7;
  int n_e = counts[e];
  if (mt * BM >= n_e) return;

  int tid = threadIdx.x;
  int lane = tid & 63;
  int wave = __builtin_amdgcn_readfirstlane(tid >> 6);
  int wm = (wave >> 1) * 64, wn = (wave & 1) * 64;
  int m16 = lane & 15, qd = lane >> 4;

  const __hip_bfloat16* gA[4];
  const __hip_bfloat16* gB[4];
#pragma unroll
  for (int i2 = 0; i2 < 4; i2++) {
    int s = i2 * 256 + tid;
    int r = s >> 3;
    int q = (s & 7) ^ (r & 7);
    // rows >= n_e: poison bytes, but row-isolated in MFMA -> discarded rows only
    gA[i2] = act + ((size_t)e * CAP + mt * BM + r) * WW + q * 8;
    gB[i2] = w2t + ((size_t)e * DD + nt * BN + r) * WW + q * 8;
  }
  short* ldsA[4];
  short* ldsB[4];
#pragma unroll
  for (int i2 = 0; i2 < 4; i2++) {
    ldsA[i2] = As + (i2 * 256 + wave * 64) * 8;
    ldsB[i2] = Bs + (i2 * 256 + wave * 64) * 8;
  }

  int aoff[4][2], boff[4][2];
#pragma unroll
  for (int mi = 0; mi < 4; mi++) {
    int r = wm + mi * 16 + m16;
#pragma unroll
    for (int h = 0; h < 2; h++)
      aoff[mi][h] = (r * 8 + ((qd + h * 4) ^ (r & 7))) * 8;
  }
#pragma unroll
  for (int ni = 0; ni < 4; ni++) {
    int r = wn + ni * 16 + m16;
#pragma unroll
    for (int h = 0; h < 2; h++)
      boff[ni][h] = (r * 8 + ((qd + h * 4) ^ (r & 7))) * 8;
  }

  f32x4 zero = {0.f, 0.f, 0.f, 0.f};
  f32x4 acc[4][4];
#pragma unroll
  for (int mi = 0; mi < 4; mi++)
#pragma unroll
    for (int ni = 0; ni < 4; ni++) acc[mi][ni] = zero;

  for (int k0 = 0; k0 < WW; k0 += BK) {
#pragma unroll
    for (int i2 = 0; i2 < 4; i2++) gload_lds16(gA[i2] + k0, ldsA[i2]);
#pragma unroll
    for (int i2 = 0; i2 < 4; i2++) gload_lds16(gB[i2] + k0, ldsB[i2]);
    __syncthreads();
#pragma unroll
    for (int h = 0; h < 2; h++) {
      bf16x8 af[4], bfr[4];
#pragma unroll
      for (int mi = 0; mi < 4; mi++) af[mi] = *(const bf16x8*)(As + aoff[mi][h]);
#pragma unroll
      for (int ni = 0; ni < 4; ni++) bfr[ni] = *(const bf16x8*)(Bs + boff[ni][h]);
#pragma unroll
      for (int mi = 0; mi < 4; mi++)
#pragma unroll
        for (int ni = 0; ni < 4; ni++)
          acc[mi][ni] = __builtin_amdgcn_mfma_f32_16x16x32_bf16(
              af[mi], bfr[ni], acc[mi][ni], 0, 0, 0);
    }
    __syncthreads();
  }

  // epilogue: raw y (routing weights applied in combine)
#pragma unroll
  for (int mi = 0; mi < 4; mi++) {
#pragma unroll
    for (int reg = 0; reg < 4; reg++) {
      int slot = mt * BM + wm + mi * 16 + qd * 4 + reg;
      if (slot < n_e) {
#pragma unroll
        for (int ni = 0; ni < 4; ni++) {
          int col = nt * BN + wn + ni * 16 + m16;
          y[((size_t)e * CAP + slot) * DD + col] = __float2bfloat16(acc[mi][ni][reg]);
        }
      }
    }
  }
}

// ---------------- combine: out[t] = w0*y[slot0] + w1*y[slot1] ----------------
__global__ __launch_bounds__(256) void combine_kernel(
    const __hip_bfloat16* __restrict__ y, const int* __restrict__ tslot,
    const float* __restrict__ wpair, float* __restrict__ out)
{
  int t = blockIdx.x;
  int c = threadIdx.x * 4;
  int s0 = tslot[2 * t], s1 = tslot[2 * t + 1];
  float w0 = wpair[2 * t], w1 = wpair[2 * t + 1];
  const unsigned short* yu = (const unsigned short*)y;
  ushort4 a = *(const ushort4*)(yu + (size_t)s0 * DD + c);
  ushort4 bq = *(const ushort4*)(yu + (size_t)s1 * DD + c);
  f32x4 o;
  o[0] = w0 * bf2f(a.x) + w1 * bf2f(bq.x);
  o[1] = w0 * bf2f(a.y) + w1 * bf2f(bq.y);
  o[2] = w0 * bf2f(a.z) + w1 * bf2f(bq.z);
  o[3] = w0 * bf2f(a.w) + w1 * bf2f(bq.w);
  *(f32x4*)(out + (size_t)t * DD + c) = o;
}

extern "C" void kernel_launch(void* const* d_in, const int* in_sizes, int n_in,
                              void* d_out, int out_size, void* d_ws, size_t ws_size,
                              hipStream_t stream)
{
  const float* x  = (const float*)d_in[0];
  const float* rw = (const float*)d_in[1];
  const float* w1 = (const float*)d_in[2];
  const float* w2 = (const float*)d_in[3];
  float* out = (float*)d_out;

  char* ws = (char*)d_ws;
  __hip_bfloat16* xb  = (__hip_bfloat16*)ws;  ws += (size_t)T_TOKENS * DD * 2;
  __hip_bfloat16* w1t = (__hip_bfloat16*)ws;  ws += (size_t)EE * WW * DD * 2;
  __hip_bfloat16* w2t = (__hip_bfloat16*)ws;  ws += (size_t)EE * DD * WW * 2;
  __hip_bfloat16* act = (__hip_bfloat16*)ws;  ws += (size_t)EE * CAP * WW * 2;
  __hip_bfloat16* y   = (__hip_bfloat16*)ws;  ws += (size_t)EE * CAP * DD * 2;
  int*   counts = (int*)ws;                   ws += 256;
  int*   idx    = (int*)ws;                   ws += (size_t)EE * CAP * 4;
  int*   sel    = (int*)ws;                   ws += (size_t)T_TOKENS * 4;
  int*   tslot  = (int*)ws;                   ws += (size_t)T_TOKENS * 8;
  float* wpair  = (float*)ws;                 ws += (size_t)T_TOKENS * 8;

  // k1: w1 transpose (512 blocks, 128x128 tiles) + router
  pre_kernel<<<TR1_BLOCKS + T_TOKENS / 4, 256, 0, stream>>>(
      w1, x, rw, w1t, xb, sel, wpair);
  // k2: deterministic contention-free list build
  build_lists<<<1, 1024, 0, stream>>>(sel, counts, idx, tslot);
  // k3: grouped GEMM1 + fused w2 transpose (512 blocks, 128x128 tiles)
  gemm1_kernel<<<GEMM_BLOCKS + TR2_BLOCKS, 256, 0, stream>>>(
      xb, w1t, counts, idx, act, w2, w2t);
  gemm2_kernel<<<GEMM_BLOCKS, 256, 0, stream>>>(act, w2t, counts, y);
  combine_kernel<<<T_TOKENS, 256, 0, stream>>>(y, tslot, wpair, out);
}